// Round 22
// baseline (168.814 us; speedup 1.0000x reference)
//
#include <hip/hip_runtime.h>
#include <hip/hip_bf16.h>

typedef __attribute__((ext_vector_type(8))) short short8;
typedef __attribute__((ext_vector_type(4))) float f32x4;

#define DEV __device__ __forceinline__

constexpr int Tn = 1024, Bn = 4, Dn = 1024, Rn = 64, Sn = 16, Mn = 64, Hn = 16;
constexpr int DH = 64;                 // head dim
constexpr int Qn = Rn + Tn + Sn;       // 1104 queries
constexpr int KL = Mn + Rn + Tn;       // 1152 keys
constexpr int NT = KL / 64;            // 18 key tiles
constexpr int QB = Qn * Bn;            // 4416 q rows
constexpr int KB = KL * Bn;            // 4608 kv rows
constexpr int MU = 4672;               // unified rows: mems(256) rc(256) utt(4096) summ(64)
constexpr size_t OUTM = (size_t)(Rn + Tn) * Bn * Dn;   // 4,456,448
constexpr size_t OUTK = OUTM + (size_t)Sn * Bn * Dn;   // 4,521,984
constexpr size_t OUTV = OUTK + (size_t)Tn * Bn * Dn;   // 8,716,288
constexpr size_t NU  = (size_t)Tn * Bn * Dn;
constexpr size_t NR_ = (size_t)Rn * Bn * Dn;
constexpr size_t NS_ = (size_t)Sn * Bn * Dn;
constexpr size_t NM_ = (size_t)Mn * Bn * Dn;
constexpr float QSCALE = 0.18033688f;  // 0.125 * log2(e), folded into Q projection

constexpr int PREP_TW = 1024;                          // transpose_w3 sub-grid
constexpr int PREP_CV = 1024;                          // convert_acts sub-grid (fp32 mode only)
constexpr int PREP_MB = (Bn * Qn * NT + 3) / 4;        // build_mbits sub-grid

DEV float b2f(ushort u) { union { unsigned v; float f; } x; x.v = ((unsigned)u) << 16; return x.f; }
DEV ushort f2b(float f) { __hip_bfloat16 h = __float2bfloat16(f); return *reinterpret_cast<ushort*>(&h); }

DEV float ldbias(const void* p, int i, int fp32) {
    return fp32 ? ((const float*)p)[i] : b2f(((const ushort*)p)[i]);
}
DEV void stout(void* p, size_t i, float v, int fp32) {
    if (fp32) ((float*)p)[i] = v; else ((ushort*)p)[i] = f2b(v);
}
DEV bool mread(const void* m, size_t idx, int mode) {
    if (mode == 0) return ((const unsigned char*)m)[idx] != 0;
    if (mode == 1) return ((const int*)m)[idx] != 0;
    return ((const float*)m)[idx] != 0.f;
}
// write a short8 of bf16 either as bf16 or widened to fp32
DEV void st8(void* gout, size_t o, short8 v, int ofp) {
    if (!ofp) {
        *(short8*)((ushort*)gout + o) = v;
    } else {
        float* f = (float*)gout + o;
#pragma unroll
        for (int j = 0; j < 8; ++j) f[j] = b2f((ushort)v[j]);
    }
}

// per-block dtype detection. bf16 N(0,1): all 64 sampled exponents sane.
DEV int detect_fp32(const ushort* utt) {
    int l = threadIdx.x & 63;
    int e = (utt[l] >> 7) & 0xFF;
    unsigned long long bal = __ballot(e > 64 && e < 192);
    return (__popcll(bal) < 58) ? 1 : 0;
}
// mask storage: 0 byte-bool, 1 int32, 2 float32
DEV int detect_mmode(const unsigned char* mask) {
    int l = threadIdx.x & 63;
    bool nz0 = false, nz2 = false;
#pragma unroll
    for (int s = 0; s < 4; ++s) {
        int wrd = l + s * 64;
        nz0 |= mask[wrd * 4] != 0;
        nz2 |= mask[wrd * 4 + 2] != 0;
    }
    unsigned long long b0 = __ballot(nz0);
    unsigned long long b2 = __ballot(nz2);
    if (b0 != 0 && b2 == 0) return 1;
    if (b0 == 0 && b2 != 0) return 2;
    return 0;
}

DEV void gload_lds16(const void* g, void* l) {
    __builtin_amdgcn_global_load_lds(
        (const __attribute__((address_space(1))) unsigned int*)g,
        (__attribute__((address_space(3))) unsigned int*)l, 16, 0, 0);
}

DEV unsigned cvt_pk_bf16(float lo, float hi) {
    unsigned r;
    asm("v_cvt_pk_bf16_f32 %0, %1, %2" : "=v"(r) : "v"(lo), "v"(hi));
    return r;
}

// virtual key order: sigma(v) = (2*(v>>5) + ((v&7)>>2))*16 + ((v>>3)&3)*4 + (v&3)
DEV int sigma_key(int v) {
    return (2 * (v >> 5) + ((v & 7) >> 2)) * 16 + ((v >> 3) & 3) * 4 + (v & 3);
}

// ---------------------------------------------------------------- merged prep kernel
__global__ __launch_bounds__(256) void prep_kernel(
    const void* utt, const void* rc, const void* sm, const void* mm,
    const void* Wq, const void* Wkv, const void* Wout,
    const void* amask, const int* __restrict__ lengths,
    ushort* dst, ushort* WqT, ushort* WkvT, ushort* WoutT,
    unsigned long long* __restrict__ mbits) {
    __shared__ alignas(16) ushort tile[64 * 64];
    const int t = threadIdx.x;
    int bid = blockIdx.x;

    if (bid < PREP_TW) {
        const int fp32 = detect_fp32((const ushort*)utt);
        const int z = bid >> 8, tr = (bid >> 4) & 15;
        int tc = bid & 15;
        const void* W; ushort* WT; int N;
        if (z == 0)      { W = Wq;   WT = WqT;   N = 1024; }
        else if (z == 3) { W = Wout; WT = WoutT; N = 1024; }
        else             { W = Wkv;  WT = WkvT;  N = 2048; tc += (z - 1) * 16; }
        const int K = 1024;
        for (int c = t; c < 512; c += 256) {
            int row = c >> 3, q = c & 7;
            int u = q ^ (row & 7);
            ushort o[8];
#pragma unroll
            for (int j = 0; j < 8; ++j) {
                size_t gi = (size_t)(tr * 64 + row) * N + tc * 64 + q * 8 + j;
                o[j] = fp32 ? f2b(((const float*)W)[gi]) : ((const ushort*)W)[gi];
            }
            *(short8*)&tile[row * 64 + u * 8] = *(short8*)o;
        }
        __syncthreads();
        for (int c = t; c < 512; c += 256) {
            int n = c >> 3, q = c & 7;
            ushort vv[8];
#pragma unroll
            for (int j = 0; j < 8; ++j) {
                int k = q * 8 + j;
                int u = (n >> 3) ^ (k & 7);
                vv[j] = tile[k * 64 + u * 8 + (n & 7)];
            }
            *(short8*)(WT + (size_t)(tc * 64 + n) * K + tr * 64 + q * 8) = *(short8*)vv;
        }
        return;
    }
    bid -= PREP_TW;
    if (bid < PREP_CV) {
        const int fp32 = detect_fp32((const ushort*)utt);
        if (!fp32) return;   // bf16 mode: gemm_qkv reads originals directly
        const size_t total = (NU + NR_ + NS_ + NM_) / 8;
        for (size_t cidx = (size_t)bid * 256 + t; cidx < total;
             cidx += (size_t)PREP_CV * 256) {
            size_t e = cidx * 8; const void* src; size_t li; ushort* d;
            if (e < NU)                  { src = utt; li = e;                 d = dst; }
            else if (e < NU + NR_)       { src = rc;  li = e - NU;            d = dst + NU; }
            else if (e < NU + NR_ + NS_) { src = sm;  li = e - NU - NR_;      d = dst + NU + NR_; }
            else                         { src = mm;  li = e - NU - NR_ - NS_; d = dst + NU + NR_ + NS_; }
            const float* f = (const float*)src + li;
            ushort o[8];
#pragma unroll
            for (int j = 0; j < 8; ++j) o[j] = f2b(f[j]);
            *(short8*)(d + li) = *(short8*)o;
        }
        return;
    }
    bid -= PREP_CV;
    const int mmode = detect_mmode((const unsigned char*)amask);
    int word = bid * 4 + (t >> 6);
    if (word >= Bn * Qn * NT) return;
    int lane = t & 63;
    int ktl = word % NT;
    int rem = word / NT;
    int q = rem % Qn;
    int b = rem / Qn;
    const int l0 = lengths[0], l1 = lengths[1], l2 = lengths[2], l3 = lengths[3];
    const int maxlen = max(max(l0, l1), max(l2, l3));
    const int klen = lengths[b] + KL - maxlen;
    int kg = ktl * 64 + lane;
    bool m = mread(amask, (size_t)q * KL + kg, mmode) || (kg >= klen);
    unsigned long long bal = __ballot(m);
    if (lane == 0) mbits[word] = bal;
}

// ---------------------------------------------------------------- transpose V + emit out_key/out_val
__global__ __launch_bounds__(256) void transpose_v(const ushort* __restrict__ kv,
                                                   ushort* __restrict__ vT,
                                                   const void* uorig, void* __restrict__ gout) {
    __shared__ alignas(16) ushort tile[64 * 64];
    const int ofp = detect_fp32((const ushort*)uorig);
    const int kt = blockIdx.x, bh = blockIdx.y;
    const int b = bh >> 4, h = bh & 15;
    const int t = threadIdx.x;
    for (int c = t; c < 512; c += 256) {
        int key = c >> 3, q = c & 7;
        int krow = kt * 64 + key;
        size_t r = (size_t)krow * Bn + b;
        short8 v = *(const short8*)(kv + r * 2048 + 1024 + h * DH + q * 8);
        int u = q ^ (key & 7);
        *(short8*)&tile[key * 64 + u * 8] = v;
        if (krow >= 128) {   // r >= 512: out_val + out_key slices (coalesced 16B)
            st8(gout, OUTV + (r - 512) * 1024 + h * DH + q * 8, v, ofp);
            short8 kk = *(const short8*)(kv + r * 2048 + h * DH + q * 8);
            st8(gout, OUTK + (r - 512) * 1024 + h * DH + q * 8, kk, ofp);
        }
    }
    __syncthreads();
    for (int c = t; c < 512; c += 256) {
        int d = c >> 3, q = c & 7;
        ushort vv[8];
#pragma unroll
        for (int j = 0; j < 8; ++j) {
            int key = sigma_key(q * 8 + j);
            int u = (d >> 3) ^ (key & 7);
            vv[j] = tile[key * 64 + u * 8 + (d & 7)];
        }
        *(short8*)(vT + ((size_t)bh * 64 + d) * KL + kt * 64 + q * 8) = *(short8*)vv;
    }
}

// ---------------------------------------------------------------- fused QKV GEMM, 128x128 tile, BK=64, 4 waves
#define Q128_STAGE(DSTBUF, KT)                                                        \
    _Pragma("unroll")                                                                 \
    for (int i2 = 0; i2 < 4; ++i2) {                                                  \
        gload_lds16(asrc[i2] + (KT) * 64, &As[DSTBUF][(i2 * 256 + t) * 8]);           \
        gload_lds16(bsrc[i2] + (KT) * 64, &Bs[DSTBUF][(i2 * 256 + t) * 8]);           \
    }

__global__ __launch_bounds__(256, 2) void gemm_qkv(
    const ushort* __restrict__ cmem, const ushort* __restrict__ crc,
    const ushort* __restrict__ cutt, const ushort* __restrict__ csum,
    const void* morig, const void* rorig, const void* uorig, const void* sorig,
    const ushort* __restrict__ Bt, const void* __restrict__ bq, const void* __restrict__ bkv,
    ushort* __restrict__ q_ws, ushort* __restrict__ kv_ws) {
    __shared__ alignas(16) ushort As[2][8192];
    __shared__ alignas(16) ushort Bs[2][8192];
    const int ofp = detect_fp32((const ushort*)uorig);
    const int t = threadIdx.x;
    const int lane = t & 63;
    const int w = t >> 6;
    const int wr = w >> 1, wc = w & 1;
    const int g = lane >> 4, lr = lane & 15;

    const ushort* s0 = ofp ? cmem : (const ushort*)morig;
    const ushort* s1 = ofp ? crc  : (const ushort*)rorig;
    const ushort* s2 = ofp ? cutt : (const ushort*)uorig;
    const ushort* s3 = ofp ? csum : (const ushort*)sorig;

    const int bid = blockIdx.x;                  // 888 blocks, %8==0
    const int wg = (bid & 7) * 111 + (bid >> 3);
    const int bx = wg % 24, by = wg / 24;
    const int mbase = by * 128, nbase = bx * 128;

    const ushort* asrc[4]; const ushort* bsrc[4];
#pragma unroll
    for (int i2 = 0; i2 < 4; ++i2) {
        int slot = i2 * 256 + t;
        int row = slot >> 3, kc = slot & 7;
        int q = kc ^ (row & 7);
        int grow = mbase + row;
        if (grow >= MU) grow = MU - 1;
        const ushort* s;
        if (grow < 256)       s = s0 + (size_t)grow * 1024;
        else if (grow < 512)  s = s1 + (size_t)(grow - 256) * 1024;
        else if (grow < 4608) s = s2 + (size_t)(grow - 512) * 1024;
        else                  s = s3 + (size_t)(grow - 4608) * 1024;
        asrc[i2] = s + q * 8;
        bsrc[i2] = Bt + (size_t)(nbase + row) * 1024 + q * 8;
    }

    f32x4 acc[4][4] = {};

    Q128_STAGE(0, 0);

    for (int kt = 0; kt < 16; ++kt) {
        const int c = kt & 1;
        if (kt + 1 < 16) {
            Q128_STAGE(c ^ 1, kt + 1);
            asm volatile("s_waitcnt vmcnt(8)" ::: "memory");
        } else {
            asm volatile("s_waitcnt vmcnt(0)" ::: "memory");
        }
        __builtin_amdgcn_sched_barrier(0);
        __builtin_amdgcn_s_barrier();

        short8 bfr[4][2];
#pragma unroll
        for (int n = 0; n < 4; ++n)
#pragma unroll
            for (int ks = 0; ks < 2; ++ks) {
                int col = wc * 64 + n * 16 + lr;
                bfr[n][ks] = *(const short8*)&Bs[c][col * 64 + (((ks * 4 + g) ^ (lr & 7)) << 3)];
            }
        short8 af[4][2];
#pragma unroll
        for (int m = 0; m < 4; ++m)
#pragma unroll
            for (int ks = 0; ks < 2; ++ks) {
                int row = wr * 64 + m * 16 + lr;
                af[m][ks] = *(const short8*)&As[c][row * 64 + (((ks * 4 + g) ^ (lr & 7)) << 3)];
            }
        __builtin_amdgcn_s_setprio(1);
#pragma unroll
        for (int m = 0; m < 4; ++m)
#pragma unroll
            for (int n = 0; n < 4; ++n) {
                acc[m][n] = __builtin_amdgcn_mfma_f32_16x16x32_bf16(af[m][0], bfr[n][0], acc[m][n], 0, 0, 0);
                acc[m][n] = __builtin_amdgcn_mfma_f32_16x16x32_bf16(af[m][1], bfr[n][1], acc[m][n], 0, 0, 0);
            }
        __builtin_amdgcn_s_setprio(0);

        __builtin_amdgcn_sched_barrier(0);
        __builtin_amdgcn_s_barrier();
    }

    // epilogue: n-innermost (L2 write-combine); out_key/out_val in transpose_v.
    float bv[4];
#pragma unroll
    for (int n = 0; n < 4; ++n) {
        int col = nbase + wc * 64 + n * 16 + lr;
        bv[n] = (col < 1024) ? ldbias(bq, col, ofp) : ldbias(bkv, col - 1024, ofp);
    }
#pragma unroll
    for (int m = 0; m < 4; ++m)
#pragma unroll
        for (int i = 0; i < 4; ++i) {
            int r = mbase + wr * 64 + m * 16 + g * 4 + i;
            if (r >= MU) continue;
#pragma unroll
            for (int n = 0; n < 4; ++n) {
                int col = nbase + wc * 64 + n * 16 + lr;
                float val = acc[m][n][i] + bv[n];
                if (col < 1024) {
                    if (r >= 256) q_ws[(size_t)(r - 256) * 1024 + col] = f2b(val * QSCALE);
                } else {
                    if (r < 4608) kv_ws[(size_t)r * 2048 + (col - 1024)] = f2b(val);
                }
            }
        }
}

// ---------------------------------------------------------------- out GEMM: 64x128 tile, BK=64, 4 waves
#define O_STAGE(DSTBUF, KT)                                                           \
    _Pragma("unroll")                                                                 \
    for (int i2 = 0; i2 < 2; ++i2)                                                    \
        gload_lds16(asrc[i2] + (KT) * 64, &As[DSTBUF][(i2 * 256 + t) * 8]);           \
    _Pragma("unroll")                                                                 \
    for (int i2 = 0; i2 < 4; ++i2)                                                    \
        gload_lds16(bsrc[i2] + (KT) * 64, &Bs[DSTBUF][(i2 * 256 + t) * 8]);

__global__ __launch_bounds__(256, 3) void gemm_out(
    const ushort* __restrict__ A, const ushort* __restrict__ Bt,
    const void* __restrict__ bias, const void* uorig, void* __restrict__ gout) {
    __shared__ alignas(16) ushort As[2][4096];
    __shared__ alignas(16) ushort Bs[2][8192];
    const int ofp = detect_fp32((const ushort*)uorig);
    const int t = threadIdx.x;
    const int lane = t & 63;
    const int w = t >> 6;
    const int wr = w >> 1, wc = w & 1;
    const int g = lane >> 4, lr = lane & 15;

    const int nwg = gridDim.x;                   // 552, %8 == 0
    const int bid = blockIdx.x;
    const int wg = (bid & 7) * (nwg >> 3) + (bid >> 3);
    const int bx = wg % 8, by = wg / 8;
    const int mbase = by * 64, nbase = bx * 128;

    const ushort* asrc[2];
#pragma unroll
    for (int i2 = 0; i2 < 2; ++i2) {
        int slot = i2 * 256 + t;
        int row = slot >> 3, kc = slot & 7, q = kc ^ (row & 7);
        asrc[i2] = A + (size_t)(mbase + row) * 1024 + q * 8;
    }
    const ushort* bsrc[4];
#pragma unroll
    for (int i2 = 0; i2 < 4; ++i2) {
        int slot = i2 * 256 + t;
        int row = slot >> 3, kc = slot & 7, q = kc ^ (row & 7);
        bsrc[i2] = Bt + (size_t)(nbase + row) * 1024 + q * 8;
    }

    f32x4 acc[2][4] = {};

    O_STAGE(0, 0);

    for (int kt = 0; kt < 16; ++kt) {
        const int c = kt & 1;
        if (kt + 1 < 16) {
            O_STAGE(c ^ 1, kt + 1);
            asm volatile("s_waitcnt vmcnt(6)" ::: "memory");
        } else {
            asm volatile("s_waitcnt vmcnt(0)" ::: "memory");
        }
        __builtin_amdgcn_sched_barrier(0);
        __builtin_amdgcn_s_barrier();

        short8 bfr[4][2];
#pragma unroll
        for (int n = 0; n < 4; ++n)
#pragma unroll
            for (int ks = 0; ks < 2; ++ks) {
                int col = wc * 64 + n * 16 + lr;
                bfr[n][ks] = *(const short8*)&Bs[c][col * 64 + (((ks * 4 + g) ^ (lr & 7)) << 3)];
            }
        short8 af[2][2];
#pragma unroll
        for (int m = 0; m < 2; ++m)
#pragma unroll
            for (int ks = 0; ks < 2; ++ks) {
                int row = wr * 32 + m * 16 + lr;
                af[m][ks] = *(const short8*)&As[c][row * 64 + (((ks * 4 + g) ^ (lr & 7)) << 3)];
            }
        __builtin_amdgcn_s_setprio(1);
#pragma unroll
        for (int m = 0; m < 2; ++m)
#pragma unroll
            for (int n = 0; n < 4; ++n) {
                acc[m][n] = __builtin_amdgcn_mfma_f32_16x16x32_bf16(af[m][0], bfr[n][0], acc[m][n], 0, 0, 0);
                acc[m][n] = __builtin_amdgcn_mfma_f32_16x16x32_bf16(af[m][1], bfr[n][1], acc[m][n], 0, 0, 0);
            }
        __builtin_amdgcn_s_setprio(0);

        __builtin_amdgcn_sched_barrier(0);
        __builtin_amdgcn_s_barrier();
    }

    float bv[4];
#pragma unroll
    for (int n = 0; n < 4; ++n) {
        int col = nbase + wc * 64 + n * 16 + lr;
        bv[n] = ldbias(bias, col, ofp);
    }
#pragma unroll
    for (int m = 0; m < 2; ++m)
#pragma unroll
        for (int i = 0; i < 4; ++i) {
            int row = mbase + wr * 32 + m * 16 + g * 4 + i;
#pragma unroll
            for (int n = 0; n < 4; ++n) {
                int col = nbase + wc * 64 + n * 16 + lr;
                float val = acc[m][n][i] + bv[n];
                if (row < (Rn + Tn) * Bn) stout(gout, (size_t)row * 1024 + col, val, ofp);
                else stout(gout, OUTM + (size_t)(row - (Rn + Tn) * Bn) * 1024 + col, tanhf(val), ofp);
            }
        }
}

// ---------------------------------------------------------------- attention: 8 waves x 16 q-rows, QBLK=128
// One staged 16KB K/V tile now feeds 128 q-rows (2x amortization of staging,
// mask loads, and barriers per q-row). Per-wave state unchanged vs R21 (no
// VGPR growth). Grid 576, LDS 32KB, bounds(512,2) -> 16 waves/CU.
// Dynamic trip count skips all-pad key tiles.
#define ATTN_STAGE(DSTBUF, KT)                                                        \
    gload_lds16(ksrc + (size_t)(KT) * kstep, &Ks[DSTBUF][t * 8]);                     \
    gload_lds16(vsrc + (size_t)(KT) * 64,    &Vs[DSTBUF][t * 8]);

__global__ __launch_bounds__(512, 2) void attn_kernel(
    const ushort* __restrict__ qws, const ushort* __restrict__ kvws, const ushort* __restrict__ vTws,
    const unsigned long long* __restrict__ mbits, const int* __restrict__ lengths,
    ushort* __restrict__ attnws) {
    __shared__ alignas(16) ushort Ks[2][64 * 64];
    __shared__ alignas(16) ushort Vs[2][64 * 64];

    const int bid = blockIdx.x;
    const int wg = (bid & 7) * (gridDim.x >> 3) + (bid >> 3);   // 576 blocks
    const int qblk = wg % 9;
    const int bh = wg / 9;
    const int b = bh >> 4, h = bh & 15;
    const int t = threadIdx.x;
    const int w = t >> 6, lane = t & 63;
    const int g = lane >> 4, lr = lane & 15;

    const int l0 = lengths[0], l1 = lengths[1], l2 = lengths[2], l3 = lengths[3];
    const int maxlen = max(max(l0, l1), max(l2, l3));
    const int klen = lengths[b] + KL - maxlen;
    const int ntb = min(NT, (klen + 63) >> 6);   // live key-tiles for this batch

    const int qi = qblk * 128 + w * 16 + lr;
    const int qic = qi < Qn ? qi : (Qn - 1);
    const ushort* qptr = qws + ((size_t)qic * Bn + b) * Dn + h * DH;
    const short8 qf0 = *(const short8*)(qptr + g * 8);
    const short8 qf1 = *(const short8*)(qptr + 32 + g * 8);
    const unsigned long long* mp = mbits + ((size_t)b * Qn + qic) * NT;

    // staging: thread t covers key/d row = t>>3, chunk = t&7 (XOR-involution source)
    const int srow = t >> 3;
    const int sw = (((t & 7) ^ (srow & 7)) << 3);
    const ushort* ksrc = kvws + ((size_t)srow * Bn + b) * 2048 + h * DH + sw;
    const ushort* vsrc = vTws + ((size_t)bh * 64 + srow) * KL + sw;
    const size_t kstep = (size_t)64 * Bn * 2048;

    f32x4 acc_o[4] = {};
    float lsum = 0.f;
    unsigned long long wbA = mp[0], wbB = 0;

    ATTN_STAGE(0, 0);

    for (int kt = 0; kt < ntb; ++kt) {
        const int c = kt & 1;
        if (kt + 1 < ntb) {
            ATTN_STAGE(c ^ 1, kt + 1);
            wbB = mp[kt + 1];
            asm volatile("s_waitcnt vmcnt(3)" ::: "memory");   // 2 stage + 1 mask in flight
        } else {
            asm volatile("s_waitcnt vmcnt(0)" ::: "memory");
        }
        __builtin_amdgcn_sched_barrier(0);
        __builtin_amdgcn_s_barrier();
        __builtin_amdgcn_sched_barrier(0);

        f32x4 sa[4] = {};
        __builtin_amdgcn_s_setprio(1);
#pragma unroll
        for (int n = 0; n < 4; ++n) {
            int key = n * 16 + lr;
            short8 kb0 = *(const short8*)&Ks[c][key * 64 + ((g ^ (key & 7)) << 3)];
            short8 kb1 = *(const short8*)&Ks[c][key * 64 + (((4 + g) ^ (key & 7)) << 3)];
            sa[n] = __builtin_amdgcn_mfma_f32_16x16x32_bf16(kb0, qf0, sa[n], 0, 0, 0);
            sa[n] = __builtin_amdgcn_mfma_f32_16x16x32_bf16(kb1, qf1, sa[n], 0, 0, 0);
        }
        __builtin_amdgcn_s_setprio(0);

        unsigned pkk[4][2];
#pragma unroll
        for (int n = 0; n < 4; ++n) {
            unsigned bits = (unsigned)(wbA >> (n * 16 + g * 4)) & 15u;
            float p[4];
#pragma unroll
            for (int i = 0; i < 4; ++i) {
                float sv = ((bits >> i) & 1u) ? -100.0f : sa[n][i];
                p[i] = exp2f(sv);
                lsum += p[i];
            }
            pkk[n][0] = cvt_pk_bf16(p[0], p[1]);
            pkk[n][1] = cvt_pk_bf16(p[2], p[3]);
        }
        union { unsigned u[4]; short8 s; } c0, c1;
        c0.u[0] = pkk[0][0]; c0.u[1] = pkk[0][1]; c0.u[2] = pkk[1][0]; c0.u[3] = pkk[1][1];
        c1.u[0] = pkk[2][0]; c1.u[1] = pkk[2][1]; c1.u[2] = pkk[3][0]; c1.u[3] = pkk[3][1];

        __builtin_amdgcn_s_setprio(1);
#pragma unroll
        for (int n = 0; n < 4; ++n) {
            int d = n * 16 + lr;
            short8 vb0 = *(const short8*)&Vs[c][d * 64 + ((g ^ (d & 7)) << 3)];
            short8 vb1 = *(const short8*)&Vs[c][d * 64 + (((4 + g) ^ (d & 7)) << 3)];
            acc_o[n] = __builtin_amdgcn_mfma_f32_16x16x32_bf16(c0.s, vb0, acc_o[n], 0, 0, 0);
            acc_o[n] = __builtin_amdgcn_mfma_f32_16x16x32_bf16(c1.s, vb1, acc_o[n], 0, 0, 0);
        }
        __builtin_amdgcn_s_setprio(0);

        wbA = wbB;
        __builtin_amdgcn_sched_barrier(0);
        __builtin_amdgcn_s_barrier();
    }

    float ls = lsum;
    ls += __shfl_xor(ls, 16);
    ls += __shfl_xor(ls, 32);
#pragma unroll
    for (int i = 0; i < 4; ++i) {
        int qrow = g * 4 + i;
        float lsv = __shfl(ls, (lane & 48) | qrow);
        int qg = qblk * 128 + w * 16 + qrow;
        if (qg >= Qn) continue;
        float inv = 1.f / lsv;
#pragma unroll
        for (int n = 0; n < 4; ++n) {
            attnws[((size_t)qg * Bn + b) * Dn + h * DH + n * 16 + lr] = f2b(acc_o[n][i] * inv);
        }
    }
}

// ---------------------------------------------------------------- launch
extern "C" void kernel_launch(void* const* d_in, const int* in_sizes, int n_in,
                              void* d_out, int out_size, void* d_ws, size_t ws_size,
                              hipStream_t stream) {
    const void* utt   = d_in[0];
    const void* rc    = d_in[1];
    const void* summ  = d_in[2];
    const void* mems  = d_in[3];
    const int*  lens  = (const int*)d_in[4];
    const void* amask = d_in[5];
    const void* Wq   = d_in[6];
    const void* bq   = d_in[7];
    const void* Wkv  = d_in[8];
    const void* bkv  = d_in[9];
    const void* Wout = d_in[10];
    const void* bout = d_in[11];

    ushort* ws    = (ushort*)d_ws;
    ushort* cu    = ws + 64;
    ushort* cutt  = cu;
    ushort* crc   = cutt + NU;
    ushort* csum  = crc + NR_;
    ushort* cmem  = csum + NS_;
    ushort* WqT   = cmem + NM_;                      // WqT|WkvT contiguous = fused (3072 x 1024) Bt
    ushort* WkvT  = WqT + (size_t)1024 * 1024;
    ushort* WoutT = WkvT + (size_t)2048 * 1024;
    ushort* q_ws  = WoutT + (size_t)1024 * 1024;
    ushort* kv_ws = q_ws + (size_t)QB * Dn;
    ushort* vT_ws = kv_ws + (size_t)KB * 2048;
    ushort* at_ws = vT_ws + (size_t)64 * 64 * KL;
    unsigned long long* mbits = (unsigned long long*)(at_ws + (size_t)QB * Dn);

    prep_kernel<<<PREP_TW + PREP_CV + PREP_MB, 256, 0, stream>>>(
        utt, rc, summ, mems, Wq, Wkv, Wout, amask, lens,
        cu, WqT, WkvT, WoutT, mbits);

    gemm_qkv<<<dim3(888), 256, 0, stream>>>(cmem, crc, cutt, csum,
                                            mems, rc, utt, summ,
                                            WqT, bq, bkv, q_ws, kv_ws);
    transpose_v<<<dim3(KL / 64, Bn * Hn), 256, 0, stream>>>(kv_ws, vT_ws, utt, d_out);
    attn_kernel<<<dim3(9 * Bn * Hn), 512, 0, stream>>>(q_ws, kv_ws, vT_ws, mbits, lens, at_ws);
    gemm_out<<<dim3(552), 256, 0, stream>>>(at_ws, WoutT, bout, utt, d_out);
}

// Round 23
// 165.687 us; speedup vs baseline: 1.0189x; 1.0189x over previous
//
#include <hip/hip_runtime.h>
#include <hip/hip_bf16.h>

typedef __attribute__((ext_vector_type(8))) short short8;
typedef __attribute__((ext_vector_type(4))) float f32x4;

#define DEV __device__ __forceinline__

constexpr int Tn = 1024, Bn = 4, Dn = 1024, Rn = 64, Sn = 16, Mn = 64, Hn = 16;
constexpr int DH = 64;                 // head dim
constexpr int Qn = Rn + Tn + Sn;       // 1104 queries
constexpr int KL = Mn + Rn + Tn;       // 1152 keys
constexpr int NT = KL / 64;            // 18 key tiles
constexpr int NQB = 18;                // q-blocks of 64
constexpr int QB = Qn * Bn;            // 4416 q rows
constexpr int KB = KL * Bn;            // 4608 kv rows
constexpr int MU = 4672;               // unified rows: mems(256) rc(256) utt(4096) summ(64)
constexpr size_t OUTM = (size_t)(Rn + Tn) * Bn * Dn;   // 4,456,448
constexpr size_t OUTK = OUTM + (size_t)Sn * Bn * Dn;   // 4,521,984
constexpr size_t OUTV = OUTK + (size_t)Tn * Bn * Dn;   // 8,716,288
constexpr size_t NU  = (size_t)Tn * Bn * Dn;
constexpr size_t NR_ = (size_t)Rn * Bn * Dn;
constexpr size_t NS_ = (size_t)Sn * Bn * Dn;
constexpr size_t NM_ = (size_t)Mn * Bn * Dn;
constexpr float QSCALE = 0.18033688f;  // 0.125 * log2(e), folded into Q projection

constexpr int PREP_TW = 1024;                          // transpose_w3 sub-grid
constexpr int PREP_CV = 1024;                          // convert_acts sub-grid (fp32 mode only)
constexpr int PREP_MB = (Bn * Qn * NT + 3) / 4;        // build_mbits sub-grid

DEV float b2f(ushort u) { union { unsigned v; float f; } x; x.v = ((unsigned)u) << 16; return x.f; }
DEV ushort f2b(float f) { __hip_bfloat16 h = __float2bfloat16(f); return *reinterpret_cast<ushort*>(&h); }

DEV float ldbias(const void* p, int i, int fp32) {
    return fp32 ? ((const float*)p)[i] : b2f(((const ushort*)p)[i]);
}
DEV void stout(void* p, size_t i, float v, int fp32) {
    if (fp32) ((float*)p)[i] = v; else ((ushort*)p)[i] = f2b(v);
}
DEV bool mread(const void* m, size_t idx, int mode) {
    if (mode == 0) return ((const unsigned char*)m)[idx] != 0;
    if (mode == 1) return ((const int*)m)[idx] != 0;
    return ((const float*)m)[idx] != 0.f;
}
// write a short8 of bf16 either as bf16 or widened to fp32
DEV void st8(void* gout, size_t o, short8 v, int ofp) {
    if (!ofp) {
        *(short8*)((ushort*)gout + o) = v;
    } else {
        float* f = (float*)gout + o;
#pragma unroll
        for (int j = 0; j < 8; ++j) f[j] = b2f((ushort)v[j]);
    }
}

// per-block dtype detection. bf16 N(0,1): all 64 sampled exponents sane.
DEV int detect_fp32(const ushort* utt) {
    int l = threadIdx.x & 63;
    int e = (utt[l] >> 7) & 0xFF;
    unsigned long long bal = __ballot(e > 64 && e < 192);
    return (__popcll(bal) < 58) ? 1 : 0;
}
// mask storage: 0 byte-bool, 1 int32, 2 float32
DEV int detect_mmode(const unsigned char* mask) {
    int l = threadIdx.x & 63;
    bool nz0 = false, nz2 = false;
#pragma unroll
    for (int s = 0; s < 4; ++s) {
        int wrd = l + s * 64;
        nz0 |= mask[wrd * 4] != 0;
        nz2 |= mask[wrd * 4 + 2] != 0;
    }
    unsigned long long b0 = __ballot(nz0);
    unsigned long long b2 = __ballot(nz2);
    if (b0 != 0 && b2 == 0) return 1;
    if (b0 == 0 && b2 != 0) return 2;
    return 0;
}

DEV void gload_lds16(const void* g, void* l) {
    __builtin_amdgcn_global_load_lds(
        (const __attribute__((address_space(1))) unsigned int*)g,
        (__attribute__((address_space(3))) unsigned int*)l, 16, 0, 0);
}

DEV unsigned cvt_pk_bf16(float lo, float hi) {
    unsigned r;
    asm("v_cvt_pk_bf16_f32 %0, %1, %2" : "=v"(r) : "v"(lo), "v"(hi));
    return r;
}

// virtual key order: sigma(v) = (2*(v>>5) + ((v&7)>>2))*16 + ((v>>3)&3)*4 + (v&3)
DEV int sigma_key(int v) {
    return (2 * (v >> 5) + ((v & 7) >> 2)) * 16 + ((v >> 3) & 3) * 4 + (v & 3);
}

// ---------------------------------------------------------------- merged prep kernel
__global__ __launch_bounds__(256) void prep_kernel(
    const void* utt, const void* rc, const void* sm, const void* mm,
    const void* Wq, const void* Wkv, const void* Wout,
    const void* amask, const int* __restrict__ lengths,
    ushort* dst, ushort* WqT, ushort* WkvT, ushort* WoutT,
    unsigned long long* __restrict__ mbits) {
    __shared__ alignas(16) ushort tile[64 * 64];
    const int t = threadIdx.x;
    int bid = blockIdx.x;

    if (bid < PREP_TW) {
        const int fp32 = detect_fp32((const ushort*)utt);
        const int z = bid >> 8, tr = (bid >> 4) & 15;
        int tc = bid & 15;
        const void* W; ushort* WT; int N;
        if (z == 0)      { W = Wq;   WT = WqT;   N = 1024; }
        else if (z == 3) { W = Wout; WT = WoutT; N = 1024; }
        else             { W = Wkv;  WT = WkvT;  N = 2048; tc += (z - 1) * 16; }
        const int K = 1024;
        for (int c = t; c < 512; c += 256) {
            int row = c >> 3, q = c & 7;
            int u = q ^ (row & 7);
            ushort o[8];
#pragma unroll
            for (int j = 0; j < 8; ++j) {
                size_t gi = (size_t)(tr * 64 + row) * N + tc * 64 + q * 8 + j;
                o[j] = fp32 ? f2b(((const float*)W)[gi]) : ((const ushort*)W)[gi];
            }
            *(short8*)&tile[row * 64 + u * 8] = *(short8*)o;
        }
        __syncthreads();
        for (int c = t; c < 512; c += 256) {
            int n = c >> 3, q = c & 7;
            ushort vv[8];
#pragma unroll
            for (int j = 0; j < 8; ++j) {
                int k = q * 8 + j;
                int u = (n >> 3) ^ (k & 7);
                vv[j] = tile[k * 64 + u * 8 + (n & 7)];
            }
            *(short8*)(WT + (size_t)(tc * 64 + n) * K + tr * 64 + q * 8) = *(short8*)vv;
        }
        return;
    }
    bid -= PREP_TW;
    if (bid < PREP_CV) {
        const int fp32 = detect_fp32((const ushort*)utt);
        if (!fp32) return;   // bf16 mode: gemm_qkv reads originals directly
        const size_t total = (NU + NR_ + NS_ + NM_) / 8;
        for (size_t cidx = (size_t)bid * 256 + t; cidx < total;
             cidx += (size_t)PREP_CV * 256) {
            size_t e = cidx * 8; const void* src; size_t li; ushort* d;
            if (e < NU)                  { src = utt; li = e;                 d = dst; }
            else if (e < NU + NR_)       { src = rc;  li = e - NU;            d = dst + NU; }
            else if (e < NU + NR_ + NS_) { src = sm;  li = e - NU - NR_;      d = dst + NU + NR_; }
            else                         { src = mm;  li = e - NU - NR_ - NS_; d = dst + NU + NR_ + NS_; }
            const float* f = (const float*)src + li;
            ushort o[8];
#pragma unroll
            for (int j = 0; j < 8; ++j) o[j] = f2b(f[j]);
            *(short8*)(d + li) = *(short8*)o;
        }
        return;
    }
    bid -= PREP_CV;
    const int mmode = detect_mmode((const unsigned char*)amask);
    int word = bid * 4 + (t >> 6);
    if (word >= Bn * Qn * NT) return;
    int lane = t & 63;
    int ktl = word % NT;
    int rem = word / NT;
    int q = rem % Qn;
    int b = rem / Qn;
    const int l0 = lengths[0], l1 = lengths[1], l2 = lengths[2], l3 = lengths[3];
    const int maxlen = max(max(l0, l1), max(l2, l3));
    const int klen = lengths[b] + KL - maxlen;
    int kg = ktl * 64 + lane;
    bool m = mread(amask, (size_t)q * KL + kg, mmode) || (kg >= klen);
    unsigned long long bal = __ballot(m);
    if (lane == 0) mbits[word] = bal;
}

// ---------------------------------------------------------------- transpose V + emit out_key/out_val
__global__ __launch_bounds__(256) void transpose_v(const ushort* __restrict__ kv,
                                                   ushort* __restrict__ vT,
                                                   const void* uorig, void* __restrict__ gout) {
    __shared__ alignas(16) ushort tile[64 * 64];
    const int ofp = detect_fp32((const ushort*)uorig);
    const int kt = blockIdx.x, bh = blockIdx.y;
    const int b = bh >> 4, h = bh & 15;
    const int t = threadIdx.x;
    for (int c = t; c < 512; c += 256) {
        int key = c >> 3, q = c & 7;
        int krow = kt * 64 + key;
        size_t r = (size_t)krow * Bn + b;
        short8 v = *(const short8*)(kv + r * 2048 + 1024 + h * DH + q * 8);
        int u = q ^ (key & 7);
        *(short8*)&tile[key * 64 + u * 8] = v;
        if (krow >= 128) {   // r >= 512: out_val + out_key slices (coalesced 16B)
            st8(gout, OUTV + (r - 512) * 1024 + h * DH + q * 8, v, ofp);
            short8 kk = *(const short8*)(kv + r * 2048 + h * DH + q * 8);
            st8(gout, OUTK + (r - 512) * 1024 + h * DH + q * 8, kk, ofp);
        }
    }
    __syncthreads();
    for (int c = t; c < 512; c += 256) {
        int d = c >> 3, q = c & 7;
        ushort vv[8];
#pragma unroll
        for (int j = 0; j < 8; ++j) {
            int key = sigma_key(q * 8 + j);
            int u = (d >> 3) ^ (key & 7);
            vv[j] = tile[key * 64 + u * 8 + (d & 7)];
        }
        *(short8*)(vT + ((size_t)bh * 64 + d) * KL + kt * 64 + q * 8) = *(short8*)vv;
    }
}

// ---------------------------------------------------------------- fused QKV GEMM, 128x128 tile, BK=64, 4 waves
#define Q128_STAGE(DSTBUF, KT)                                                        \
    _Pragma("unroll")                                                                 \
    for (int i2 = 0; i2 < 4; ++i2) {                                                  \
        gload_lds16(asrc[i2] + (KT) * 64, &As[DSTBUF][(i2 * 256 + t) * 8]);           \
        gload_lds16(bsrc[i2] + (KT) * 64, &Bs[DSTBUF][(i2 * 256 + t) * 8]);           \
    }

__global__ __launch_bounds__(256, 2) void gemm_qkv(
    const ushort* __restrict__ cmem, const ushort* __restrict__ crc,
    const ushort* __restrict__ cutt, const ushort* __restrict__ csum,
    const void* morig, const void* rorig, const void* uorig, const void* sorig,
    const ushort* __restrict__ Bt, const void* __restrict__ bq, const void* __restrict__ bkv,
    ushort* __restrict__ q_ws, ushort* __restrict__ kv_ws) {
    __shared__ alignas(16) ushort As[2][8192];
    __shared__ alignas(16) ushort Bs[2][8192];
    const int ofp = detect_fp32((const ushort*)uorig);
    const int t = threadIdx.x;
    const int lane = t & 63;
    const int w = t >> 6;
    const int wr = w >> 1, wc = w & 1;
    const int g = lane >> 4, lr = lane & 15;

    const ushort* s0 = ofp ? cmem : (const ushort*)morig;
    const ushort* s1 = ofp ? crc  : (const ushort*)rorig;
    const ushort* s2 = ofp ? cutt : (const ushort*)uorig;
    const ushort* s3 = ofp ? csum : (const ushort*)sorig;

    const int bid = blockIdx.x;                  // 888 blocks, %8==0
    const int wg = (bid & 7) * 111 + (bid >> 3);
    const int bx = wg % 24, by = wg / 24;
    const int mbase = by * 128, nbase = bx * 128;

    const ushort* asrc[4]; const ushort* bsrc[4];
#pragma unroll
    for (int i2 = 0; i2 < 4; ++i2) {
        int slot = i2 * 256 + t;
        int row = slot >> 3, kc = slot & 7;
        int q = kc ^ (row & 7);
        int grow = mbase + row;
        if (grow >= MU) grow = MU - 1;
        const ushort* s;
        if (grow < 256)       s = s0 + (size_t)grow * 1024;
        else if (grow < 512)  s = s1 + (size_t)(grow - 256) * 1024;
        else if (grow < 4608) s = s2 + (size_t)(grow - 512) * 1024;
        else                  s = s3 + (size_t)(grow - 4608) * 1024;
        asrc[i2] = s + q * 8;
        bsrc[i2] = Bt + (size_t)(nbase + row) * 1024 + q * 8;
    }

    f32x4 acc[4][4] = {};

    Q128_STAGE(0, 0);

    for (int kt = 0; kt < 16; ++kt) {
        const int c = kt & 1;
        if (kt + 1 < 16) {
            Q128_STAGE(c ^ 1, kt + 1);
            asm volatile("s_waitcnt vmcnt(8)" ::: "memory");
        } else {
            asm volatile("s_waitcnt vmcnt(0)" ::: "memory");
        }
        __builtin_amdgcn_sched_barrier(0);
        __builtin_amdgcn_s_barrier();

        short8 bfr[4][2];
#pragma unroll
        for (int n = 0; n < 4; ++n)
#pragma unroll
            for (int ks = 0; ks < 2; ++ks) {
                int col = wc * 64 + n * 16 + lr;
                bfr[n][ks] = *(const short8*)&Bs[c][col * 64 + (((ks * 4 + g) ^ (lr & 7)) << 3)];
            }
        short8 af[4][2];
#pragma unroll
        for (int m = 0; m < 4; ++m)
#pragma unroll
            for (int ks = 0; ks < 2; ++ks) {
                int row = wr * 64 + m * 16 + lr;
                af[m][ks] = *(const short8*)&As[c][row * 64 + (((ks * 4 + g) ^ (lr & 7)) << 3)];
            }
        __builtin_amdgcn_s_setprio(1);
#pragma unroll
        for (int m = 0; m < 4; ++m)
#pragma unroll
            for (int n = 0; n < 4; ++n) {
                acc[m][n] = __builtin_amdgcn_mfma_f32_16x16x32_bf16(af[m][0], bfr[n][0], acc[m][n], 0, 0, 0);
                acc[m][n] = __builtin_amdgcn_mfma_f32_16x16x32_bf16(af[m][1], bfr[n][1], acc[m][n], 0, 0, 0);
            }
        __builtin_amdgcn_s_setprio(0);

        __builtin_amdgcn_sched_barrier(0);
        __builtin_amdgcn_s_barrier();
    }

    // epilogue: n-innermost (L2 write-combine); out_key/out_val in transpose_v.
    float bv[4];
#pragma unroll
    for (int n = 0; n < 4; ++n) {
        int col = nbase + wc * 64 + n * 16 + lr;
        bv[n] = (col < 1024) ? ldbias(bq, col, ofp) : ldbias(bkv, col - 1024, ofp);
    }
#pragma unroll
    for (int m = 0; m < 4; ++m)
#pragma unroll
        for (int i = 0; i < 4; ++i) {
            int r = mbase + wr * 64 + m * 16 + g * 4 + i;
            if (r >= MU) continue;
#pragma unroll
            for (int n = 0; n < 4; ++n) {
                int col = nbase + wc * 64 + n * 16 + lr;
                float val = acc[m][n][i] + bv[n];
                if (col < 1024) {
                    if (r >= 256) q_ws[(size_t)(r - 256) * 1024 + col] = f2b(val * QSCALE);
                } else {
                    if (r < 4608) kv_ws[(size_t)r * 2048 + (col - 1024)] = f2b(val);
                }
            }
        }
}

// ---------------------------------------------------------------- out GEMM: 64x128 tile, BK=64, 4 waves
#define O_STAGE(DSTBUF, KT)                                                           \
    _Pragma("unroll")                                                                 \
    for (int i2 = 0; i2 < 2; ++i2)                                                    \
        gload_lds16(asrc[i2] + (KT) * 64, &As[DSTBUF][(i2 * 256 + t) * 8]);           \
    _Pragma("unroll")                                                                 \
    for (int i2 = 0; i2 < 4; ++i2)                                                    \
        gload_lds16(bsrc[i2] + (KT) * 64, &Bs[DSTBUF][(i2 * 256 + t) * 8]);

__global__ __launch_bounds__(256, 3) void gemm_out(
    const ushort* __restrict__ A, const ushort* __restrict__ Bt,
    const void* __restrict__ bias, const void* uorig, void* __restrict__ gout) {
    __shared__ alignas(16) ushort As[2][4096];
    __shared__ alignas(16) ushort Bs[2][8192];
    const int ofp = detect_fp32((const ushort*)uorig);
    const int t = threadIdx.x;
    const int lane = t & 63;
    const int w = t >> 6;
    const int wr = w >> 1, wc = w & 1;
    const int g = lane >> 4, lr = lane & 15;

    const int nwg = gridDim.x;                   // 552, %8 == 0
    const int bid = blockIdx.x;
    const int wg = (bid & 7) * (nwg >> 3) + (bid >> 3);
    const int bx = wg % 8, by = wg / 8;
    const int mbase = by * 64, nbase = bx * 128;

    const ushort* asrc[2];
#pragma unroll
    for (int i2 = 0; i2 < 2; ++i2) {
        int slot = i2 * 256 + t;
        int row = slot >> 3, kc = slot & 7, q = kc ^ (row & 7);
        asrc[i2] = A + (size_t)(mbase + row) * 1024 + q * 8;
    }
    const ushort* bsrc[4];
#pragma unroll
    for (int i2 = 0; i2 < 4; ++i2) {
        int slot = i2 * 256 + t;
        int row = slot >> 3, kc = slot & 7, q = kc ^ (row & 7);
        bsrc[i2] = Bt + (size_t)(nbase + row) * 1024 + q * 8;
    }

    f32x4 acc[2][4] = {};

    O_STAGE(0, 0);

    for (int kt = 0; kt < 16; ++kt) {
        const int c = kt & 1;
        if (kt + 1 < 16) {
            O_STAGE(c ^ 1, kt + 1);
            asm volatile("s_waitcnt vmcnt(6)" ::: "memory");
        } else {
            asm volatile("s_waitcnt vmcnt(0)" ::: "memory");
        }
        __builtin_amdgcn_sched_barrier(0);
        __builtin_amdgcn_s_barrier();

        short8 bfr[4][2];
#pragma unroll
        for (int n = 0; n < 4; ++n)
#pragma unroll
            for (int ks = 0; ks < 2; ++ks) {
                int col = wc * 64 + n * 16 + lr;
                bfr[n][ks] = *(const short8*)&Bs[c][col * 64 + (((ks * 4 + g) ^ (lr & 7)) << 3)];
            }
        short8 af[2][2];
#pragma unroll
        for (int m = 0; m < 2; ++m)
#pragma unroll
            for (int ks = 0; ks < 2; ++ks) {
                int row = wr * 32 + m * 16 + lr;
                af[m][ks] = *(const short8*)&As[c][row * 64 + (((ks * 4 + g) ^ (lr & 7)) << 3)];
            }
        __builtin_amdgcn_s_setprio(1);
#pragma unroll
        for (int m = 0; m < 2; ++m)
#pragma unroll
            for (int n = 0; n < 4; ++n) {
                acc[m][n] = __builtin_amdgcn_mfma_f32_16x16x32_bf16(af[m][0], bfr[n][0], acc[m][n], 0, 0, 0);
                acc[m][n] = __builtin_amdgcn_mfma_f32_16x16x32_bf16(af[m][1], bfr[n][1], acc[m][n], 0, 0, 0);
            }
        __builtin_amdgcn_s_setprio(0);

        __builtin_amdgcn_sched_barrier(0);
        __builtin_amdgcn_s_barrier();
    }

    float bv[4];
#pragma unroll
    for (int n = 0; n < 4; ++n) {
        int col = nbase + wc * 64 + n * 16 + lr;
        bv[n] = ldbias(bias, col, ofp);
    }
#pragma unroll
    for (int m = 0; m < 2; ++m)
#pragma unroll
        for (int i = 0; i < 4; ++i) {
            int row = mbase + wr * 32 + m * 16 + g * 4 + i;
#pragma unroll
            for (int n = 0; n < 4; ++n) {
                int col = nbase + wc * 64 + n * 16 + lr;
                float val = acc[m][n][i] + bv[n];
                if (row < (Rn + Tn) * Bn) stout(gout, (size_t)row * 1024 + col, val, ofp);
                else stout(gout, OUTM + (size_t)(row - (Rn + Tn) * Bn) * 1024 + col, tanhf(val), ofp);
            }
        }
}

// ---------------------------------------------------------------- attention (4 waves x 16 q-rows, QBLK=64)
// Best-measured config (R20/R21): grid 1152, bounds(256,5), vmcnt(4),
// dynamic trip count skips all-pad key tiles.
#define ATTN_STAGE(DSTBUF, KT)                                                        \
    gload_lds16(ksrc0 + (size_t)(KT) * kstep, &Ks[DSTBUF][w * 1024]);                 \
    gload_lds16(ksrc1 + (size_t)(KT) * kstep, &Ks[DSTBUF][w * 1024 + 512]);           \
    gload_lds16(vsrc0 + (size_t)(KT) * 64,    &Vs[DSTBUF][w * 1024]);                 \
    gload_lds16(vsrc1 + (size_t)(KT) * 64,    &Vs[DSTBUF][w * 1024 + 512]);

__global__ __launch_bounds__(256, 5) void attn_kernel(
    const ushort* __restrict__ qws, const ushort* __restrict__ kvws, const ushort* __restrict__ vTws,
    const unsigned long long* __restrict__ mbits, const int* __restrict__ lengths,
    ushort* __restrict__ attnws) {
    __shared__ alignas(16) ushort Ks[2][64 * 64];
    __shared__ alignas(16) ushort Vs[2][64 * 64];

    const int bid = blockIdx.x;
    const int wg = (bid & 7) * (gridDim.x >> 3) + (bid >> 3);
    const int qblk = wg % NQB;
    const int bh = wg / NQB;
    const int b = bh >> 4, h = bh & 15;
    const int t = threadIdx.x;
    const int w = t >> 6, lane = t & 63;
    const int g = lane >> 4, lr = lane & 15;

    const int l0 = lengths[0], l1 = lengths[1], l2 = lengths[2], l3 = lengths[3];
    const int maxlen = max(max(l0, l1), max(l2, l3));
    const int klen = lengths[b] + KL - maxlen;
    const int ntb = min(NT, (klen + 63) >> 6);   // live key-tiles for this batch

    const int qi = qblk * 64 + w * 16 + lr;
    const int qic = qi < Qn ? qi : (Qn - 1);
    const ushort* qptr = qws + ((size_t)qic * Bn + b) * Dn + h * DH;
    const short8 qf0 = *(const short8*)(qptr + g * 8);
    const short8 qf1 = *(const short8*)(qptr + 32 + g * 8);
    const unsigned long long* mp = mbits + ((size_t)b * Qn + qic) * NT;

    const int srow0 = w * 16 + (lane >> 3);
    const int srow1 = srow0 + 8;
    const int sw = (((lane & 7) ^ ((lane >> 3) & 7)) << 3);
    const ushort* ksrc0 = kvws + ((size_t)srow0 * Bn + b) * 2048 + h * DH + sw;
    const ushort* ksrc1 = kvws + ((size_t)srow1 * Bn + b) * 2048 + h * DH + sw;
    const ushort* vsrc0 = vTws + ((size_t)bh * 64 + srow0) * KL + sw;
    const ushort* vsrc1 = vTws + ((size_t)bh * 64 + srow1) * KL + sw;
    const size_t kstep = (size_t)64 * Bn * 2048;

    f32x4 acc_o[4] = {};
    float lsum = 0.f;
    unsigned long long wbA = mp[0], wbB = 0;

    ATTN_STAGE(0, 0);

    for (int kt = 0; kt < ntb; ++kt) {
        const int c = kt & 1;
        if (kt + 1 < ntb) {
            ATTN_STAGE(c ^ 1, kt + 1);
            wbB = mp[kt + 1];
            asm volatile("s_waitcnt vmcnt(4)" ::: "memory");
        } else {
            asm volatile("s_waitcnt vmcnt(0)" ::: "memory");
        }
        __builtin_amdgcn_sched_barrier(0);
        __builtin_amdgcn_s_barrier();
        __builtin_amdgcn_sched_barrier(0);

        f32x4 sa[4] = {};
        __builtin_amdgcn_s_setprio(1);
#pragma unroll
        for (int n = 0; n < 4; ++n) {
            int key = n * 16 + lr;
            short8 kb0 = *(const short8*)&Ks[c][key * 64 + ((g ^ (key & 7)) << 3)];
            short8 kb1 = *(const short8*)&Ks[c][key * 64 + (((4 + g) ^ (key & 7)) << 3)];
            sa[n] = __builtin_amdgcn_mfma_f32_16x16x32_bf16(kb0, qf0, sa[n], 0, 0, 0);
            sa[n] = __builtin_amdgcn_mfma_f32_16x16x32_bf16(kb1, qf1, sa[n], 0, 0, 0);
        }
        __builtin_amdgcn_s_setprio(0);

        unsigned pkk[4][2];
#pragma unroll
        for (int n = 0; n < 4; ++n) {
            unsigned bits = (unsigned)(wbA >> (n * 16 + g * 4)) & 15u;
            float p[4];
#pragma unroll
            for (int i = 0; i < 4; ++i) {
                float sv = ((bits >> i) & 1u) ? -100.0f : sa[n][i];
                p[i] = exp2f(sv);
                lsum += p[i];
            }
            pkk[n][0] = cvt_pk_bf16(p[0], p[1]);
            pkk[n][1] = cvt_pk_bf16(p[2], p[3]);
        }
        union { unsigned u[4]; short8 s; } c0, c1;
        c0.u[0] = pkk[0][0]; c0.u[1] = pkk[0][1]; c0.u[2] = pkk[1][0]; c0.u[3] = pkk[1][1];
        c1.u[0] = pkk[2][0]; c1.u[1] = pkk[2][1]; c1.u[2] = pkk[3][0]; c1.u[3] = pkk[3][1];

        __builtin_amdgcn_s_setprio(1);
#pragma unroll
        for (int n = 0; n < 4; ++n) {
            int d = n * 16 + lr;
            short8 vb0 = *(const short8*)&Vs[c][d * 64 + ((g ^ (d & 7)) << 3)];
            short8 vb1 = *(const short8*)&Vs[c][d * 64 + (((4 + g) ^ (d & 7)) << 3)];
            acc_o[n] = __builtin_amdgcn_mfma_f32_16x16x32_bf16(c0.s, vb0, acc_o[n], 0, 0, 0);
            acc_o[n] = __builtin_amdgcn_mfma_f32_16x16x32_bf16(c1.s, vb1, acc_o[n], 0, 0, 0);
        }
        __builtin_amdgcn_s_setprio(0);

        wbA = wbB;
        __builtin_amdgcn_sched_barrier(0);
        __builtin_amdgcn_s_barrier();
    }

    float ls = lsum;
    ls += __shfl_xor(ls, 16);
    ls += __shfl_xor(ls, 32);
#pragma unroll
    for (int i = 0; i < 4; ++i) {
        int qrow = g * 4 + i;
        float lsv = __shfl(ls, (lane & 48) | qrow);
        int qg = qblk * 64 + w * 16 + qrow;
        if (qg >= Qn) continue;
        float inv = 1.f / lsv;
#pragma unroll
        for (int n = 0; n < 4; ++n) {
            attnws[((size_t)qg * Bn + b) * Dn + h * DH + n * 16 + lr] = f2b(acc_o[n][i] * inv);
        }
    }
}

// ---------------------------------------------------------------- launch
extern "C" void kernel_launch(void* const* d_in, const int* in_sizes, int n_in,
                              void* d_out, int out_size, void* d_ws, size_t ws_size,
                              hipStream_t stream) {
    const void* utt   = d_in[0];
    const void* rc    = d_in[1];
    const void* summ  = d_in[2];
    const void* mems  = d_in[3];
    const int*  lens  = (const int*)d_in[4];
    const void* amask = d_in[5];
    const void* Wq   = d_in[6];
    const void* bq   = d_in[7];
    const void* Wkv  = d_in[8];
    const void* bkv  = d_in[9];
    const void* Wout = d_in[10];
    const void* bout = d_in[11];

    ushort* ws    = (ushort*)d_ws;
    ushort* cu    = ws + 64;
    ushort* cutt  = cu;
    ushort* crc   = cutt + NU;
    ushort* csum  = crc + NR_;
    ushort* cmem  = csum + NS_;
    ushort* WqT   = cmem + NM_;                      // WqT|WkvT contiguous = fused (3072 x 1024) Bt
    ushort* WkvT  = WqT + (size_t)1024 * 1024;
    ushort* WoutT = WkvT + (size_t)2048 * 1024;
    ushort* q_ws  = WoutT + (size_t)1024 * 1024;
    ushort* kv_ws = q_ws + (size_t)QB * Dn;
    ushort* vT_ws = kv_ws + (size_t)KB * 2048;
    ushort* at_ws = vT_ws + (size_t)64 * 64 * KL;
    unsigned long long* mbits = (unsigned long long*)(at_ws + (size_t)QB * Dn);

    prep_kernel<<<PREP_TW + PREP_CV + PREP_MB, 256, 0, stream>>>(
        utt, rc, summ, mems, Wq, Wkv, Wout, amask, lens,
        cu, WqT, WkvT, WoutT, mbits);

    gemm_qkv<<<dim3(888), 256, 0, stream>>>(cmem, crc, cutt, csum,
                                            mems, rc, utt, summ,
                                            WqT, bq, bkv, q_ws, kv_ws);
    transpose_v<<<dim3(KL / 64, Bn * Hn), 256, 0, stream>>>(kv_ws, vT_ws, utt, d_out);
    attn_kernel<<<dim3(NQB * Bn * Hn), 256, 0, stream>>>(q_ws, kv_ws, vT_ws, mbits, lens, at_ws);
    gemm_out<<<dim3(552), 256, 0, stream>>>(at_ws, WoutT, bout, utt, d_out);
}

// Round 24
// 163.269 us; speedup vs baseline: 1.0340x; 1.0148x over previous
//
#include <hip/hip_runtime.h>
#include <hip/hip_bf16.h>

typedef __attribute__((ext_vector_type(8))) short short8;
typedef __attribute__((ext_vector_type(4))) float f32x4;

#define DEV __device__ __forceinline__

constexpr int Tn = 1024, Bn = 4, Dn = 1024, Rn = 64, Sn = 16, Mn = 64, Hn = 16;
constexpr int DH = 64;                 // head dim
constexpr int Qn = Rn + Tn + Sn;       // 1104 queries
constexpr int KL = Mn + Rn + Tn;       // 1152 keys
constexpr int NT = KL / 64;            // 18 key tiles
constexpr int NQB = 18;                // q-blocks of 64
constexpr int QB = Qn * Bn;            // 4416 q rows
constexpr int KB = KL * Bn;            // 4608 kv rows
constexpr int MU = 4672;               // unified rows: mems(256) rc(256) utt(4096) summ(64)
constexpr size_t OUTM = (size_t)(Rn + Tn) * Bn * Dn;   // 4,456,448
constexpr size_t OUTK = OUTM + (size_t)Sn * Bn * Dn;   // 4,521,984
constexpr size_t OUTV = OUTK + (size_t)Tn * Bn * Dn;   // 8,716,288
constexpr size_t NU  = (size_t)Tn * Bn * Dn;
constexpr size_t NR_ = (size_t)Rn * Bn * Dn;
constexpr size_t NS_ = (size_t)Sn * Bn * Dn;
constexpr size_t NM_ = (size_t)Mn * Bn * Dn;
constexpr float QSCALE = 0.18033688f;  // 0.125 * log2(e), folded into Q projection

constexpr int PREP_TW = 1024;                          // transpose_w3 sub-grid
constexpr int PREP_CV = 1024;                          // convert_acts sub-grid (fp32 mode only)
constexpr int PREP_MB = (Bn * Qn * NT + 3) / 4;        // build_mbits sub-grid

DEV float b2f(ushort u) { union { unsigned v; float f; } x; x.v = ((unsigned)u) << 16; return x.f; }
DEV ushort f2b(float f) { __hip_bfloat16 h = __float2bfloat16(f); return *reinterpret_cast<ushort*>(&h); }

DEV float ldbias(const void* p, int i, int fp32) {
    return fp32 ? ((const float*)p)[i] : b2f(((const ushort*)p)[i]);
}
DEV void stout(void* p, size_t i, float v, int fp32) {
    if (fp32) ((float*)p)[i] = v; else ((ushort*)p)[i] = f2b(v);
}
DEV bool mread(const void* m, size_t idx, int mode) {
    if (mode == 0) return ((const unsigned char*)m)[idx] != 0;
    if (mode == 1) return ((const int*)m)[idx] != 0;
    return ((const float*)m)[idx] != 0.f;
}
// write a short8 of bf16 either as bf16 or widened to fp32
DEV void st8(void* gout, size_t o, short8 v, int ofp) {
    if (!ofp) {
        *(short8*)((ushort*)gout + o) = v;
    } else {
        float* f = (float*)gout + o;
#pragma unroll
        for (int j = 0; j < 8; ++j) f[j] = b2f((ushort)v[j]);
    }
}

// per-block dtype detection. bf16 N(0,1): all 64 sampled exponents sane.
DEV int detect_fp32(const ushort* utt) {
    int l = threadIdx.x & 63;
    int e = (utt[l] >> 7) & 0xFF;
    unsigned long long bal = __ballot(e > 64 && e < 192);
    return (__popcll(bal) < 58) ? 1 : 0;
}
// mask storage: 0 byte-bool, 1 int32, 2 float32
DEV int detect_mmode(const unsigned char* mask) {
    int l = threadIdx.x & 63;
    bool nz0 = false, nz2 = false;
#pragma unroll
    for (int s = 0; s < 4; ++s) {
        int wrd = l + s * 64;
        nz0 |= mask[wrd * 4] != 0;
        nz2 |= mask[wrd * 4 + 2] != 0;
    }
    unsigned long long b0 = __ballot(nz0);
    unsigned long long b2 = __ballot(nz2);
    if (b0 != 0 && b2 == 0) return 1;
    if (b0 == 0 && b2 != 0) return 2;
    return 0;
}

DEV void gload_lds16(const void* g, void* l) {
    __builtin_amdgcn_global_load_lds(
        (const __attribute__((address_space(1))) unsigned int*)g,
        (__attribute__((address_space(3))) unsigned int*)l, 16, 0, 0);
}

DEV unsigned cvt_pk_bf16(float lo, float hi) {
    unsigned r;
    asm("v_cvt_pk_bf16_f32 %0, %1, %2" : "=v"(r) : "v"(lo), "v"(hi));
    return r;
}

// virtual key order: sigma(v) = (2*(v>>5) + ((v&7)>>2))*16 + ((v>>3)&3)*4 + (v&3)
DEV int sigma_key(int v) {
    return (2 * (v >> 5) + ((v & 7) >> 2)) * 16 + ((v >> 3) & 3) * 4 + (v & 3);
}

// ---------------------------------------------------------------- merged prep kernel
__global__ __launch_bounds__(256) void prep_kernel(
    const void* utt, const void* rc, const void* sm, const void* mm,
    const void* Wq, const void* Wkv, const void* Wout,
    const void* amask, const int* __restrict__ lengths,
    ushort* dst, ushort* WqT, ushort* WkvT, ushort* WoutT,
    unsigned long long* __restrict__ mbits) {
    __shared__ alignas(16) ushort tile[64 * 64];
    const int t = threadIdx.x;
    int bid = blockIdx.x;

    if (bid < PREP_TW) {
        const int fp32 = detect_fp32((const ushort*)utt);
        const int z = bid >> 8, tr = (bid >> 4) & 15;
        int tc = bid & 15;
        const void* W; ushort* WT; int N;
        if (z == 0)      { W = Wq;   WT = WqT;   N = 1024; }
        else if (z == 3) { W = Wout; WT = WoutT; N = 1024; }
        else             { W = Wkv;  WT = WkvT;  N = 2048; tc += (z - 1) * 16; }
        const int K = 1024;
        for (int c = t; c < 512; c += 256) {
            int row = c >> 3, q = c & 7;
            int u = q ^ (row & 7);
            ushort o[8];
#pragma unroll
            for (int j = 0; j < 8; ++j) {
                size_t gi = (size_t)(tr * 64 + row) * N + tc * 64 + q * 8 + j;
                o[j] = fp32 ? f2b(((const float*)W)[gi]) : ((const ushort*)W)[gi];
            }
            *(short8*)&tile[row * 64 + u * 8] = *(short8*)o;
        }
        __syncthreads();
        for (int c = t; c < 512; c += 256) {
            int n = c >> 3, q = c & 7;
            ushort vv[8];
#pragma unroll
            for (int j = 0; j < 8; ++j) {
                int k = q * 8 + j;
                int u = (n >> 3) ^ (k & 7);
                vv[j] = tile[k * 64 + u * 8 + (n & 7)];
            }
            *(short8*)(WT + (size_t)(tc * 64 + n) * K + tr * 64 + q * 8) = *(short8*)vv;
        }
        return;
    }
    bid -= PREP_TW;
    if (bid < PREP_CV) {
        const int fp32 = detect_fp32((const ushort*)utt);
        if (!fp32) return;   // bf16 mode: gemm_qkv reads originals directly
        const size_t total = (NU + NR_ + NS_ + NM_) / 8;
        for (size_t cidx = (size_t)bid * 256 + t; cidx < total;
             cidx += (size_t)PREP_CV * 256) {
            size_t e = cidx * 8; const void* src; size_t li; ushort* d;
            if (e < NU)                  { src = utt; li = e;                 d = dst; }
            else if (e < NU + NR_)       { src = rc;  li = e - NU;            d = dst + NU; }
            else if (e < NU + NR_ + NS_) { src = sm;  li = e - NU - NR_;      d = dst + NU + NR_; }
            else                         { src = mm;  li = e - NU - NR_ - NS_; d = dst + NU + NR_ + NS_; }
            const float* f = (const float*)src + li;
            ushort o[8];
#pragma unroll
            for (int j = 0; j < 8; ++j) o[j] = f2b(f[j]);
            *(short8*)(d + li) = *(short8*)o;
        }
        return;
    }
    bid -= PREP_CV;
    const int mmode = detect_mmode((const unsigned char*)amask);
    int word = bid * 4 + (t >> 6);
    if (word >= Bn * Qn * NT) return;
    int lane = t & 63;
    int ktl = word % NT;
    int rem = word / NT;
    int q = rem % Qn;
    int b = rem / Qn;
    const int l0 = lengths[0], l1 = lengths[1], l2 = lengths[2], l3 = lengths[3];
    const int maxlen = max(max(l0, l1), max(l2, l3));
    const int klen = lengths[b] + KL - maxlen;
    int kg = ktl * 64 + lane;
    bool m = mread(amask, (size_t)q * KL + kg, mmode) || (kg >= klen);
    unsigned long long bal = __ballot(m);
    if (lane == 0) mbits[word] = bal;
}

// ---------------------------------------------------------------- transpose V + emit out_key/out_val
__global__ __launch_bounds__(256) void transpose_v(const ushort* __restrict__ kv,
                                                   ushort* __restrict__ vT,
                                                   const void* uorig, void* __restrict__ gout) {
    __shared__ alignas(16) ushort tile[64 * 64];
    const int ofp = detect_fp32((const ushort*)uorig);
    const int kt = blockIdx.x, bh = blockIdx.y;
    const int b = bh >> 4, h = bh & 15;
    const int t = threadIdx.x;
    for (int c = t; c < 512; c += 256) {
        int key = c >> 3, q = c & 7;
        int krow = kt * 64 + key;
        size_t r = (size_t)krow * Bn + b;
        short8 v = *(const short8*)(kv + r * 2048 + 1024 + h * DH + q * 8);
        int u = q ^ (key & 7);
        *(short8*)&tile[key * 64 + u * 8] = v;
        if (krow >= 128) {   // r >= 512: out_val + out_key slices (coalesced 16B)
            st8(gout, OUTV + (r - 512) * 1024 + h * DH + q * 8, v, ofp);
            short8 kk = *(const short8*)(kv + r * 2048 + h * DH + q * 8);
            st8(gout, OUTK + (r - 512) * 1024 + h * DH + q * 8, kk, ofp);
        }
    }
    __syncthreads();
    for (int c = t; c < 512; c += 256) {
        int d = c >> 3, q = c & 7;
        ushort vv[8];
#pragma unroll
        for (int j = 0; j < 8; ++j) {
            int key = sigma_key(q * 8 + j);
            int u = (d >> 3) ^ (key & 7);
            vv[j] = tile[key * 64 + u * 8 + (d & 7)];
        }
        *(short8*)(vT + ((size_t)bh * 64 + d) * KL + kt * 64 + q * 8) = *(short8*)vv;
    }
}

// ---------------------------------------------------------------- fused QKV GEMM, 128x128 tile, BK=64, 8 WAVES
// Same tile/LDS/staging as the 75us 4-wave version, but 8 waves (64x32 output
// each) -> 4 waves/SIMD at 2 blocks/CU: doubles the independent instruction
// streams available to hide the per-tile latency bubble (MfmaUtil 15% = 2
// waves/SIMD x 154 MFMA-cyc / ~2000-cyc tile; 4 streams should compress it).
#define Q128_STAGE(DSTBUF, KT)                                                        \
    _Pragma("unroll")                                                                 \
    for (int i2 = 0; i2 < 2; ++i2) {                                                  \
        gload_lds16(asrc[i2] + (KT) * 64, &As[DSTBUF][(i2 * 512 + t) * 8]);           \
        gload_lds16(bsrc[i2] + (KT) * 64, &Bs[DSTBUF][(i2 * 512 + t) * 8]);           \
    }

__global__ __launch_bounds__(512, 2) void gemm_qkv(
    const ushort* __restrict__ cmem, const ushort* __restrict__ crc,
    const ushort* __restrict__ cutt, const ushort* __restrict__ csum,
    const void* morig, const void* rorig, const void* uorig, const void* sorig,
    const ushort* __restrict__ Bt, const void* __restrict__ bq, const void* __restrict__ bkv,
    ushort* __restrict__ q_ws, ushort* __restrict__ kv_ws) {
    __shared__ alignas(16) ushort As[2][8192];   // [128 rows][64 k] x2 = 32 KB
    __shared__ alignas(16) ushort Bs[2][8192];   // 32 KB
    const int ofp = detect_fp32((const ushort*)uorig);
    const int t = threadIdx.x;                   // 0..511
    const int lane = t & 63;
    const int w = t >> 6;                        // 0..7
    const int wr = w >> 2, wc = w & 3;           // 2M x 4N wave grid, 64x32 per wave
    const int g = lane >> 4, lr = lane & 15;

    const ushort* s0 = ofp ? cmem : (const ushort*)morig;
    const ushort* s1 = ofp ? crc  : (const ushort*)rorig;
    const ushort* s2 = ofp ? cutt : (const ushort*)uorig;
    const ushort* s3 = ofp ? csum : (const ushort*)sorig;

    const int bid = blockIdx.x;                  // 888 blocks, %8==0
    const int wg = (bid & 7) * 111 + (bid >> 3);
    const int bx = wg % 24, by = wg / 24;
    const int mbase = by * 128, nbase = bx * 128;

    // staging: slot = i2*512 + t (0..1023); row = slot>>3 (0..127), kc = slot&7,
    // src chunk q = kc^(row&7) (XOR involution within one 128B k-row)
    const ushort* asrc[2]; const ushort* bsrc[2];
#pragma unroll
    for (int i2 = 0; i2 < 2; ++i2) {
        int slot = i2 * 512 + t;
        int row = slot >> 3, kc = slot & 7;
        int q = kc ^ (row & 7);
        int grow = mbase + row;
        if (grow >= MU) grow = MU - 1;
        const ushort* s;
        if (grow < 256)       s = s0 + (size_t)grow * 1024;
        else if (grow < 512)  s = s1 + (size_t)(grow - 256) * 1024;
        else if (grow < 4608) s = s2 + (size_t)(grow - 512) * 1024;
        else                  s = s3 + (size_t)(grow - 4608) * 1024;
        asrc[i2] = s + q * 8;
        bsrc[i2] = Bt + (size_t)(nbase + row) * 1024 + q * 8;
    }

    f32x4 acc[4][2] = {};

    Q128_STAGE(0, 0);

    for (int kt = 0; kt < 16; ++kt) {
        const int c = kt & 1;
        if (kt + 1 < 16) {
            Q128_STAGE(c ^ 1, kt + 1);
            asm volatile("s_waitcnt vmcnt(4)" ::: "memory");   // tile kt done; kt+1 in flight
        } else {
            asm volatile("s_waitcnt vmcnt(0)" ::: "memory");
        }
        __builtin_amdgcn_sched_barrier(0);
        __builtin_amdgcn_s_barrier();

        short8 bfr[2][2];
#pragma unroll
        for (int n = 0; n < 2; ++n)
#pragma unroll
            for (int ks = 0; ks < 2; ++ks) {
                int col = wc * 32 + n * 16 + lr;
                bfr[n][ks] = *(const short8*)&Bs[c][col * 64 + (((ks * 4 + g) ^ (lr & 7)) << 3)];
            }
        short8 af[4][2];
#pragma unroll
        for (int m = 0; m < 4; ++m)
#pragma unroll
            for (int ks = 0; ks < 2; ++ks) {
                int row = wr * 64 + m * 16 + lr;
                af[m][ks] = *(const short8*)&As[c][row * 64 + (((ks * 4 + g) ^ (lr & 7)) << 3)];
            }
        __builtin_amdgcn_s_setprio(1);
#pragma unroll
        for (int m = 0; m < 4; ++m)
#pragma unroll
            for (int n = 0; n < 2; ++n) {
                acc[m][n] = __builtin_amdgcn_mfma_f32_16x16x32_bf16(af[m][0], bfr[n][0], acc[m][n], 0, 0, 0);
                acc[m][n] = __builtin_amdgcn_mfma_f32_16x16x32_bf16(af[m][1], bfr[n][1], acc[m][n], 0, 0, 0);
            }
        __builtin_amdgcn_s_setprio(0);

        __builtin_amdgcn_sched_barrier(0);
        __builtin_amdgcn_s_barrier();
    }

    // epilogue: n-innermost (L2 write-combine); out_key/out_val in transpose_v.
    float bv[2];
#pragma unroll
    for (int n = 0; n < 2; ++n) {
        int col = nbase + wc * 32 + n * 16 + lr;
        bv[n] = (col < 1024) ? ldbias(bq, col, ofp) : ldbias(bkv, col - 1024, ofp);
    }
#pragma unroll
    for (int m = 0; m < 4; ++m)
#pragma unroll
        for (int i = 0; i < 4; ++i) {
            int r = mbase + wr * 64 + m * 16 + g * 4 + i;
            if (r >= MU) continue;
#pragma unroll
            for (int n = 0; n < 2; ++n) {
                int col = nbase + wc * 32 + n * 16 + lr;
                float val = acc[m][n][i] + bv[n];
                if (col < 1024) {
                    if (r >= 256) q_ws[(size_t)(r - 256) * 1024 + col] = f2b(val * QSCALE);
                } else {
                    if (r < 4608) kv_ws[(size_t)r * 2048 + (col - 1024)] = f2b(val);
                }
            }
        }
}

// ---------------------------------------------------------------- out GEMM: 64x128 tile, BK=64, 4 waves
#define O_STAGE(DSTBUF, KT)                                                           \
    _Pragma("unroll")                                                                 \
    for (int i2 = 0; i2 < 2; ++i2)                                                    \
        gload_lds16(asrc[i2] + (KT) * 64, &As[DSTBUF][(i2 * 256 + t) * 8]);           \
    _Pragma("unroll")                                                                 \
    for (int i2 = 0; i2 < 4; ++i2)                                                    \
        gload_lds16(bsrc[i2] + (KT) * 64, &Bs[DSTBUF][(i2 * 256 + t) * 8]);

__global__ __launch_bounds__(256, 3) void gemm_out(
    const ushort* __restrict__ A, const ushort* __restrict__ Bt,
    const void* __restrict__ bias, const void* uorig, void* __restrict__ gout) {
    __shared__ alignas(16) ushort As[2][4096];
    __shared__ alignas(16) ushort Bs[2][8192];
    const int ofp = detect_fp32((const ushort*)uorig);
    const int t = threadIdx.x;
    const int lane = t & 63;
    const int w = t >> 6;
    const int wr = w >> 1, wc = w & 1;
    const int g = lane >> 4, lr = lane & 15;

    const int nwg = gridDim.x;                   // 552, %8 == 0
    const int bid = blockIdx.x;
    const int wg = (bid & 7) * (nwg >> 3) + (bid >> 3);
    const int bx = wg % 8, by = wg / 8;
    const int mbase = by * 64, nbase = bx * 128;

    const ushort* asrc[2];
#pragma unroll
    for (int i2 = 0; i2 < 2; ++i2) {
        int slot = i2 * 256 + t;
        int row = slot >> 3, kc = slot & 7, q = kc ^ (row & 7);
        asrc[i2] = A + (size_t)(mbase + row) * 1024 + q * 8;
    }
    const ushort* bsrc[4];
#pragma unroll
    for (int i2 = 0; i2 < 4; ++i2) {
        int slot = i2 * 256 + t;
        int row = slot >> 3, kc = slot & 7, q = kc ^ (row & 7);
        bsrc[i2] = Bt + (size_t)(nbase + row) * 1024 + q * 8;
    }

    f32x4 acc[2][4] = {};

    O_STAGE(0, 0);

    for (int kt = 0; kt < 16; ++kt) {
        const int c = kt & 1;
        if (kt + 1 < 16) {
            O_STAGE(c ^ 1, kt + 1);
            asm volatile("s_waitcnt vmcnt(6)" ::: "memory");
        } else {
            asm volatile("s_waitcnt vmcnt(0)" ::: "memory");
        }
        __builtin_amdgcn_sched_barrier(0);
        __builtin_amdgcn_s_barrier();

        short8 bfr[4][2];
#pragma unroll
        for (int n = 0; n < 4; ++n)
#pragma unroll
            for (int ks = 0; ks < 2; ++ks) {
                int col = wc * 64 + n * 16 + lr;
                bfr[n][ks] = *(const short8*)&Bs[c][col * 64 + (((ks * 4 + g) ^ (lr & 7)) << 3)];
            }
        short8 af[2][2];
#pragma unroll
        for (int m = 0; m < 2; ++m)
#pragma unroll
            for (int ks = 0; ks < 2; ++ks) {
                int row = wr * 32 + m * 16 + lr;
                af[m][ks] = *(const short8*)&As[c][row * 64 + (((ks * 4 + g) ^ (lr & 7)) << 3)];
            }
        __builtin_amdgcn_s_setprio(1);
#pragma unroll
        for (int m = 0; m < 2; ++m)
#pragma unroll
            for (int n = 0; n < 4; ++n) {
                acc[m][n] = __builtin_amdgcn_mfma_f32_16x16x32_bf16(af[m][0], bfr[n][0], acc[m][n], 0, 0, 0);
                acc[m][n] = __builtin_amdgcn_mfma_f32_16x16x32_bf16(af[m][1], bfr[n][1], acc[m][n], 0, 0, 0);
            }
        __builtin_amdgcn_s_setprio(0);

        __builtin_amdgcn_sched_barrier(0);
        __builtin_amdgcn_s_barrier();
    }

    float bv[4];
#pragma unroll
    for (int n = 0; n < 4; ++n) {
        int col = nbase + wc * 64 + n * 16 + lr;
        bv[n] = ldbias(bias, col, ofp);
    }
#pragma unroll
    for (int m = 0; m < 2; ++m)
#pragma unroll
        for (int i = 0; i < 4; ++i) {
            int row = mbase + wr * 32 + m * 16 + g * 4 + i;
#pragma unroll
            for (int n = 0; n < 4; ++n) {
                int col = nbase + wc * 64 + n * 16 + lr;
                float val = acc[m][n][i] + bv[n];
                if (row < (Rn + Tn) * Bn) stout(gout, (size_t)row * 1024 + col, val, ofp);
                else stout(gout, OUTM + (size_t)(row - (Rn + Tn) * Bn) * 1024 + col, tanhf(val), ofp);
            }
        }
}

// ---------------------------------------------------------------- attention (4 waves x 16 q-rows, QBLK=64)
// Best-measured config: grid 1152, bounds(256,5), vmcnt(4), dynamic trip count.
#define ATTN_STAGE(DSTBUF, KT)                                                        \
    gload_lds16(ksrc0 + (size_t)(KT) * kstep, &Ks[DSTBUF][w * 1024]);                 \
    gload_lds16(ksrc1 + (size_t)(KT) * kstep, &Ks[DSTBUF][w * 1024 + 512]);           \
    gload_lds16(vsrc0 + (size_t)(KT) * 64,    &Vs[DSTBUF][w * 1024]);                 \
    gload_lds16(vsrc1 + (size_t)(KT) * 64,    &Vs[DSTBUF][w * 1024 + 512]);

__global__ __launch_bounds__(256, 5) void attn_kernel(
    const ushort* __restrict__ qws, const ushort* __restrict__ kvws, const ushort* __restrict__ vTws,
    const unsigned long long* __restrict__ mbits, const int* __restrict__ lengths,
    ushort* __restrict__ attnws) {
    __shared__ alignas(16) ushort Ks[2][64 * 64];
    __shared__ alignas(16) ushort Vs[2][64 * 64];

    const int bid = blockIdx.x;
    const int wg = (bid & 7) * (gridDim.x >> 3) + (bid >> 3);
    const int qblk = wg % NQB;
    const int bh = wg / NQB;
    const int b = bh >> 4, h = bh & 15;
    const int t = threadIdx.x;
    const int w = t >> 6, lane = t & 63;
    const int g = lane >> 4, lr = lane & 15;

    const int l0 = lengths[0], l1 = lengths[1], l2 = lengths[2], l3 = lengths[3];
    const int maxlen = max(max(l0, l1), max(l2, l3));
    const int klen = lengths[b] + KL - maxlen;
    const int ntb = min(NT, (klen + 63) >> 6);   // live key-tiles for this batch

    const int qi = qblk * 64 + w * 16 + lr;
    const int qic = qi < Qn ? qi : (Qn - 1);
    const ushort* qptr = qws + ((size_t)qic * Bn + b) * Dn + h * DH;
    const short8 qf0 = *(const short8*)(qptr + g * 8);
    const short8 qf1 = *(const short8*)(qptr + 32 + g * 8);
    const unsigned long long* mp = mbits + ((size_t)b * Qn + qic) * NT;

    const int srow0 = w * 16 + (lane >> 3);
    const int srow1 = srow0 + 8;
    const int sw = (((lane & 7) ^ ((lane >> 3) & 7)) << 3);
    const ushort* ksrc0 = kvws + ((size_t)srow0 * Bn + b) * 2048 + h * DH + sw;
    const ushort* ksrc1 = kvws + ((size_t)srow1 * Bn + b) * 2048 + h * DH + sw;
    const ushort* vsrc0 = vTws + ((size_t)bh * 64 + srow0) * KL + sw;
    const ushort* vsrc1 = vTws + ((size_t)bh * 64 + srow1) * KL + sw;
    const size_t kstep = (size_t)64 * Bn * 2048;

    f32x4 acc_o[4] = {};
    float lsum = 0.f;
    unsigned long long wbA = mp[0], wbB = 0;

    ATTN_STAGE(0, 0);

    for (int kt = 0; kt < ntb; ++kt) {
        const int c = kt & 1;
        if (kt + 1 < ntb) {
            ATTN_STAGE(c ^ 1, kt + 1);
            wbB = mp[kt + 1];
            asm volatile("s_waitcnt vmcnt(4)" ::: "memory");
        } else {
            asm volatile("s_waitcnt vmcnt(0)" ::: "memory");
        }
        __builtin_amdgcn_sched_barrier(0);
        __builtin_amdgcn_s_barrier();
        __builtin_amdgcn_sched_barrier(0);

        f32x4 sa[4] = {};
        __builtin_amdgcn_s_setprio(1);
#pragma unroll
        for (int n = 0; n < 4; ++n) {
            int key = n * 16 + lr;
            short8 kb0 = *(const short8*)&Ks[c][key * 64 + ((g ^ (key & 7)) << 3)];
            short8 kb1 = *(const short8*)&Ks[c][key * 64 + (((4 + g) ^ (key & 7)) << 3)];
            sa[n] = __builtin_amdgcn_mfma_f32_16x16x32_bf16(kb0, qf0, sa[n], 0, 0, 0);
            sa[n] = __builtin_amdgcn_mfma_f32_16x16x32_bf16(kb1, qf1, sa[n], 0, 0, 0);
        }
        __builtin_amdgcn_s_setprio(0);

        unsigned pkk[4][2];
#pragma unroll
        for (int n = 0; n < 4; ++n) {
            unsigned bits = (unsigned)(wbA >> (n * 16 + g * 4)) & 15u;
            float p[4];
#pragma unroll
            for (int i = 0; i < 4; ++i) {
                float sv = ((bits >> i) & 1u) ? -100.0f : sa[n][i];
                p[i] = exp2f(sv);
                lsum += p[i];
            }
            pkk[n][0] = cvt_pk_bf16(p[0], p[1]);
            pkk[n][1] = cvt_pk_bf16(p[2], p[3]);
        }
        union { unsigned u[4]; short8 s; } c0, c1;
        c0.u[0] = pkk[0][0]; c0.u[1] = pkk[0][1]; c0.u[2] = pkk[1][0]; c0.u[3] = pkk[1][1];
        c1.u[0] = pkk[2][0]; c1.u[1] = pkk[2][1]; c1.u[2] = pkk[3][0]; c1.u[3] = pkk[3][1];

        __builtin_amdgcn_s_setprio(1);
#pragma unroll
        for (int n = 0; n < 4; ++n) {
            int d = n * 16 + lr;
            short8 vb0 = *(const short8*)&Vs[c][d * 64 + ((g ^ (d & 7)) << 3)];
            short8 vb1 = *(const short8*)&Vs[c][d * 64 + (((4 + g) ^ (d & 7)) << 3)];
            acc_o[n] = __builtin_amdgcn_mfma_f32_16x16x32_bf16(c0.s, vb0, acc_o[n], 0, 0, 0);
            acc_o[n] = __builtin_amdgcn_mfma_f32_16x16x32_bf16(c1.s, vb1, acc_o[n], 0, 0, 0);
        }
        __builtin_amdgcn_s_setprio(0);

        wbA = wbB;
        __builtin_amdgcn_sched_barrier(0);
        __builtin_amdgcn_s_barrier();
    }

    float ls = lsum;
    ls += __shfl_xor(ls, 16);
    ls += __shfl_xor(ls, 32);
#pragma unroll
    for (int i = 0; i < 4; ++i) {
        int qrow = g * 4 + i;
        float lsv = __shfl(ls, (lane & 48) | qrow);
        int qg = qblk * 64 + w * 16 + qrow;
        if (qg >= Qn) continue;
        float inv = 1.f / lsv;
#pragma unroll
        for (int n = 0; n < 4; ++n) {
            attnws[((size_t)qg * Bn + b) * Dn + h * DH + n * 16 + lr] = f2b(acc_o[n][i] * inv);
        }
    }
}

// ---------------------------------------------------------------- launch
extern "C" void kernel_launch(void* const* d_in, const int* in_sizes, int n_in,
                              void* d_out, int out_size, void* d_ws, size_t ws_size,
                              hipStream_t stream) {
    const void* utt   = d_in[0];
    const void* rc    = d_in[1];
    const void* summ  = d_in[2];
    const void* mems  = d_in[3];
    const int*  lens  = (const int*)d_in[4];
    const void* amask = d_in[5];
    const void* Wq   = d_in[6];
    const void* bq   = d_in[7];
    const void* Wkv  = d_in[8];
    const void* bkv  = d_in[9];
    const void* Wout = d_in[10];
    const void* bout = d_in[11];

    ushort* ws    = (ushort*)d_ws;
    ushort* cu    = ws + 64;
    ushort* cutt  = cu;
    ushort* crc   = cutt + NU;
    ushort* csum  = crc + NR_;
    ushort* cmem  = csum + NS_;
    ushort* WqT   = cmem + NM_;                      // WqT|WkvT contiguous = fused (3072 x 1024) Bt
    ushort* WkvT  = WqT + (size_t)1024 * 1024;
    ushort* WoutT = WkvT + (size_t)2048 * 1024;
    ushort* q_ws  = WoutT + (size_t)1024 * 1024;
    ushort* kv_ws = q_ws + (size_t)QB * Dn;
    ushort* vT_ws = kv_ws + (size_t)KB * 2048;
    ushort* at_ws = vT_ws + (size_t)64 * 64 * KL;
    unsigned long long* mbits = (unsigned long long*)(at_ws + (size_t)QB * Dn);

    prep_kernel<<<PREP_TW + PREP_CV + PREP_MB, 256, 0, stream>>>(
        utt, rc, summ, mems, Wq, Wkv, Wout, amask, lens,
        cu, WqT, WkvT, WoutT, mbits);

    gemm_qkv<<<dim3(888), 512, 0, stream>>>(cmem, crc, cutt, csum,
                                            mems, rc, utt, summ,
                                            WqT, bq, bkv, q_ws, kv_ws);
    transpose_v<<<dim3(KL / 64, Bn * Hn), 256, 0, stream>>>(kv_ws, vT_ws, utt, d_out);
    attn_kernel<<<dim3(NQB * Bn * Hn), 256, 0, stream>>>(q_ws, kv_ws, vT_ws, mbits, lens, at_ws);
    gemm_out<<<dim3(552), 256, 0, stream>>>(at_ws, WoutT, bout, utt, d_out);
}